// Round 24
// baseline (91.165 us; speedup 1.0000x reference)
//
#include <hip/hip_runtime.h>
#include <hip/hip_bf16.h>

typedef __attribute__((ext_vector_type(8))) short bfrag8;           // 8 bf16
typedef __attribute__((ext_vector_type(8))) unsigned short u16x8;
typedef __attribute__((ext_vector_type(4))) float f32x4;
typedef __attribute__((ext_vector_type(16))) float f32x16;          // 32x32 MFMA C/D
typedef __attribute__((ext_vector_type(4))) unsigned int u32x4;

static constexpr int L_ = 2048;
static constexpr int H_ = 16;
static constexpr int D_ = 64;
static constexpr int ROWSTRIDE = H_ * D_;
static constexpr int BSTRIDE = L_ * H_ * D_;
static constexpr size_t NPH = (size_t)L_ * D_;
static constexpr size_t NTOT = (size_t)4 * H_ * L_ * D_;

// Finite "minus infinity" for masking (exp2(NEG - FIXM) == 0 exactly).
static constexpr float NEG = -1e30f;
// Fixed softmax reference max (exp2 domain); normalizer cancels in O = PV/l.
static constexpr float FIXM = 24.0f;
// (1/sqrt(D)) * log2(e): folded into Q at load time -> scores in exp2 domain.
static constexpr float QS = 0.125f * 1.44269504088896341f;

__device__ __forceinline__ unsigned short f2bf(float f) {
  return __builtin_bit_cast(unsigned short, __float2bfloat16(f));
}
__device__ __forceinline__ unsigned int pack2(float lo, float hi) {
  return (unsigned int)f2bf(lo) | ((unsigned int)f2bf(hi) << 16);
}

// Cross-half (lane i <-> i+32) sum via permlane32_swap builtin (verified r6).
__device__ __forceinline__ float crosshalf_sum(float x) {
  const unsigned xu = __builtin_bit_cast(unsigned int, x);
  auto r = __builtin_amdgcn_permlane32_swap(xu, xu, false, false);
  return __builtin_bit_cast(float, (unsigned int)r[0]) +
         __builtin_bit_cast(float, (unsigned int)r[1]);
}

// ---------------------------------------------------------------------------
// Prep: f32 [B,L,H,D] -> bf16 Kb[B,H,L,D], Vt[B,H,D,L].  (Q not prepped.)
// ---------------------------------------------------------------------------
__global__ __launch_bounds__(256, 4)
void prep_kernel(const float* __restrict__ K, const float* __restrict__ V,
                 unsigned short* __restrict__ Kb, unsigned short* __restrict__ Vt) {
  const int bid = blockIdx.x;
  const int lt = bid & 31;
  const int bh = bid >> 5;
  const int h = bh & 15;
  const int b = bh >> 4;
  const int l0 = lt * 64;
  const int t = threadIdx.x;
  const int lr = t >> 2;
  const int dc = t & 3;

  __shared__ __align__(16) unsigned short vt[64 * 64];

  const size_t src = ((size_t)(b * L_ + l0 + lr) * H_ + h) * D_ + dc * 16;
  const size_t dst = ((size_t)bh * L_ + l0 + lr) * D_ + dc * 16;

  {
    f32x4 a = *(const f32x4*)(K + src),     b4 = *(const f32x4*)(K + src + 4),
          c4 = *(const f32x4*)(K + src + 8), d4 = *(const f32x4*)(K + src + 12);
    u16x8 o0, o1;
#pragma unroll
    for (int j = 0; j < 4; ++j) {
      o0[j] = f2bf(a[j]);  o0[j + 4] = f2bf(b4[j]);
      o1[j] = f2bf(c4[j]); o1[j + 4] = f2bf(d4[j]);
    }
    *(u16x8*)(Kb + dst) = o0;
    *(u16x8*)(Kb + dst + 8) = o1;
  }
  {
    f32x4 a = *(const f32x4*)(V + src),     b4 = *(const f32x4*)(V + src + 4),
          c4 = *(const f32x4*)(V + src + 8), d4 = *(const f32x4*)(V + src + 12);
    u16x8 o0, o1;
#pragma unroll
    for (int j = 0; j < 4; ++j) {
      o0[j] = f2bf(a[j]);  o0[j + 4] = f2bf(b4[j]);
      o1[j] = f2bf(c4[j]); o1[j + 4] = f2bf(d4[j]);
    }
    const int r7 = (lr + (lr >> 3)) & 7;
    *(u16x8*)&vt[lr * 64 + (((dc * 2) ^ r7) * 8)] = o0;
    *(u16x8*)&vt[lr * 64 + (((dc * 2 + 1) ^ r7) * 8)] = o1;
  }
  __syncthreads();
  {
    const int d = t >> 2;
    const int lc = t & 3;
    const int ch = d >> 3, dl = d & 7;
    u16x8 o0, o1;
#pragma unroll
    for (int i = 0; i < 8; ++i) {
      const int r0 = lc * 16 + i;
      const int r1 = lc * 16 + 8 + i;
      o0[i] = vt[r0 * 64 + ((ch ^ ((r0 + (r0 >> 3)) & 7)) * 8) + dl];
      o1[i] = vt[r1 * 64 + ((ch ^ ((r1 + (r1 >> 3)) & 7)) * 8) + dl];
    }
    const size_t vd = ((size_t)bh * D_ + d) * L_ + l0 + lc * 16;
    *(u16x8*)(Vt + vd) = o0;
    *(u16x8*)(Vt + vd + 8) = o1;
  }
}

// ---------------------------------------------------------------------------
// KVBLK=64 convoy flash attention (deep-ILP regime).
// r23 diagnosis: per-SIMD VALU only ~16%; latency-bound at ~12 waves/CU with
// shallow per-wave ILP. This kernel moves toward the guide's deep-register
// regime: block = 4 adjacent q-tiles (wave wv -> qt=4g+wv), each iteration
// processes a PAIR of kv-tiles (two independent sacc chains -> 2x softmax
// ILP, barriers per unit work halved). Staged pair serves 4 q-tiles
// (reuse 4: staging instrs + FETCH halve vs r23). No merge phase (each wave
// owns its q-tile fully). Q staged coalesced [128][64] f32, 16B-chunk XOR
// swizzle (fills arena exactly; dies before kv slabs overlay).
// launch_bounds(256,2): 256-VGPR budget (peak audit ~140). Loosening, not
// tightening (r17 erratum was TIGHTENING). All LDS addrs arithmetic (r19).
// Spill tripwire: WRITE_SIZE >> 33MB -> revert to r23.
// ---------------------------------------------------------------------------
__global__ __launch_bounds__(256, 2)
void mha_fwd_c64(const float* __restrict__ Qf,
                 const unsigned short* __restrict__ Kb,
                 const unsigned short* __restrict__ Vt,
                 float* __restrict__ Op) {
  const int bid = blockIdx.x;
  const int plane = bid & 63;               // b*16 + h
  const int g = 15 - (bid >> 6);            // group, longest first
  const int h = plane & 15;
  const int b = plane >> 4;

  const int tid = threadIdx.x;
  const int wv = tid >> 6;                  // 0..3: wave's q-tile
  const int lane = tid & 63;
  const int q = lane & 31;
  const int hi = lane >> 5;

  const int qt = 4 * g + wv;                // this wave's q-tile
  const int qr0 = qt * 32;
  const int P = 2 * g + 2;                  // kv PAIRS staged by the block

  // 32KB arena: qstage [128][64] f32 (prologue) -> kv slabs:
  // K slab (buf*2+tile)*4096, V at +16384.
  __shared__ __align__(16) unsigned char arena[32768];
  float* qstage = (float*)arena;

  const unsigned short* Kh = Kb + (size_t)plane * NPH;
  const unsigned short* Vh = Vt + (size_t)plane * NPH;
  float* Ob = Op + (size_t)b * BSTRIDE + (size_t)h * D_;

  // staging roles (fixed per thread), XOR-chunk swizzle (write == read)
  const int kr = tid >> 3, kc = tid & 7;    // K: row 0..31, 16B chunk 0..7
  const int vr = tid >> 2, vc = tid & 3;    // V^T: row 0..63, 16B chunk 0..3
  const int kOff = kr * 64 + ((kc ^ (kr & 7)) * 8);   // elements
  const int vOff = vr * 32 + ((vc ^ (vr & 3)) * 8);

  // ---- kv pair-0 loads issued FIRST (written to LDS after Q staging) ----
  u16x8 k0 = *(const u16x8*)(Kh + (size_t)kr * D_ + kc * 8);
  u16x8 v0 = *(const u16x8*)(Vh + (size_t)vr * L_ + vc * 8);
  u16x8 k1 = *(const u16x8*)(Kh + (size_t)(32 + kr) * D_ + kc * 8);
  u16x8 v1 = *(const u16x8*)(Vh + (size_t)vr * L_ + 32 + vc * 8);

  // ---- coalesced Q staging: 128 rows x 256B; 2048 chunks, 8 per thread ----
  {
    const float* qbase = Qf + ((size_t)(b * L_ + 128 * g)) * ROWSTRIDE + h * D_;
#pragma unroll
    for (int i = 0; i < 8; ++i) {
      const int c4 = tid + 256 * i;         // chunk id 0..2047
      const int row = c4 >> 4;              // 0..127
      const int cin = c4 & 15;              // 16B chunk within row
      const f32x4 v = *(const f32x4*)(qbase + (size_t)row * ROWSTRIDE + cin * 4);
      *(f32x4*)&qstage[row * 64 + ((cin ^ (row & 15)) * 4)] = v;
    }
  }
  __syncthreads();

  // Q B-frags from LDS (cvt+scale in-reg): lane holds Q[qr0+q][16s+8hi+j]
  bfrag8 qB[4];
#pragma unroll
  for (int s = 0; s < 4; ++s) {
    const int row = 32 * wv + q;
    const int c0 = 4 * s + 2 * hi;          // first 16B chunk of this frag
    const f32x4 lo = *(const f32x4*)&qstage[row * 64 + ((c0 ^ (row & 15)) * 4)];
    const f32x4 hi4 = *(const f32x4*)&qstage[row * 64 + (((c0 + 1) ^ (row & 15)) * 4)];
    bfrag8 f;
#pragma unroll
    for (int j = 0; j < 4; ++j) {
      f[j]     = (short)f2bf(lo[j] * QS);
      f[j + 4] = (short)f2bf(hi4[j] * QS);
    }
    qB[s] = f;
  }
  __syncthreads();                           // qstage dead; arena -> kv slabs

  // write kv pair 0 into buf 0
  *(u16x8*)((unsigned short*)(arena) + kOff) = k0;
  *(u16x8*)((unsigned short*)(arena + 4096) + kOff) = k1;
  *(u16x8*)((unsigned short*)(arena + 16384) + vOff) = v0;
  *(u16x8*)((unsigned short*)(arena + 16384 + 4096) + vOff) = v1;
  __syncthreads();

  float lp = 0.f;
  f32x16 o0 = {};                            // O[q][d = crow + 0..31]
  f32x16 o1 = {};                            // O[q][d = crow + 32..63]

  for (int k = 0; k < P; ++k) {
    const int cur = k & 1;
    const int t0 = 2 * k;                    // this pair's two kv-tiles
    const int t1 = 2 * k + 1;
    const bool more = (k + 1 < P);
    const bool do0 = (t0 <= qt);             // wave-uniform guards
    const bool do1 = (t1 <= qt);

    // 1) issue next pair's global loads
    u16x8 kn0, vn0, kn1, vn1;
    if (more) {
      const int base = (k + 1) * 64;
      kn0 = *(const u16x8*)(Kh + (size_t)(base + kr) * D_ + kc * 8);
      vn0 = *(const u16x8*)(Vh + (size_t)vr * L_ + base + vc * 8);
      kn1 = *(const u16x8*)(Kh + (size_t)(base + 32 + kr) * D_ + kc * 8);
      vn1 = *(const u16x8*)(Vh + (size_t)vr * L_ + base + 32 + vc * 8);
    }

    // 2) QK for both tiles (independent MFMA chains; loads land underneath)
    f32x16 sa = {}, sb = {};
    if (do0) {
      const unsigned short* kbp =
          (const unsigned short*)(arena + (size_t)(cur * 2) * 4096);
      bfrag8 kA[4];
#pragma unroll
      for (int s = 0; s < 4; ++s)
        kA[s] = *(const bfrag8*)&kbp[q * 64 + (((2 * s + hi) ^ (q & 7)) * 8)];
      __builtin_amdgcn_s_setprio(1);
#pragma unroll
      for (int s = 0; s < 4; ++s)
        sa = __builtin_amdgcn_mfma_f32_32x32x16_bf16(kA[s], qB[s], sa, 0, 0, 0);
      __builtin_amdgcn_s_setprio(0);
    }
    if (do1) {
      const unsigned short* kbp =
          (const unsigned short*)(arena + (size_t)(cur * 2 + 1) * 4096);
      bfrag8 kA[4];
#pragma unroll
      for (int s = 0; s < 4; ++s)
        kA[s] = *(const bfrag8*)&kbp[q * 64 + (((2 * s + hi) ^ (q & 7)) * 8)];
      __builtin_amdgcn_s_setprio(1);
#pragma unroll
      for (int s = 0; s < 4; ++s)
        sb = __builtin_amdgcn_mfma_f32_32x32x16_bf16(kA[s], qB[s], sb, 0, 0, 0);
      __builtin_amdgcn_s_setprio(0);
    }

    // 3) RELEASE staged regs (die before softmax/PV)
    if (more) {
      unsigned char* kslab = arena + (size_t)((cur ^ 1) * 2) * 4096;
      unsigned char* vslab = arena + 16384 + (size_t)((cur ^ 1) * 2) * 4096;
      *(u16x8*)((unsigned short*)kslab + kOff) = kn0;
      *(u16x8*)((unsigned short*)(kslab + 4096) + kOff) = kn1;
      *(u16x8*)((unsigned short*)vslab + vOff) = vn0;
      *(u16x8*)((unsigned short*)(vslab + 4096) + vOff) = vn1;
    }

    // 4) softmax + PV, tile 0 then tile 1 (exp2 chains independent)
    if (do0) {
      if (t0 == qt) {
#pragma unroll
        for (int r = 0; r < 16; ++r) {
          const int crow = (r & 3) + 8 * (r >> 2) + 4 * hi;
          if (crow > q) sa[r] = NEG;
        }
      }
#pragma unroll
      for (int r = 0; r < 16; ++r) sa[r] = __builtin_exp2f(sa[r] - FIXM);
      {
        float s8[8];
#pragma unroll
        for (int r = 0; r < 8; ++r) s8[r] = sa[2 * r] + sa[2 * r + 1];
#pragma unroll
        for (int r = 0; r < 4; ++r) s8[r] += s8[r + 4];
        lp += (s8[0] + s8[2]) + (s8[1] + s8[3]);
      }
      const unsigned int a0 = pack2(sa[0],  sa[1]),  a1 = pack2(sa[2],  sa[3]);
      const unsigned int a2 = pack2(sa[4],  sa[5]),  a3 = pack2(sa[6],  sa[7]);
      const unsigned int a4 = pack2(sa[8],  sa[9]),  a5 = pack2(sa[10], sa[11]);
      const unsigned int a6 = pack2(sa[12], sa[13]), a7 = pack2(sa[14], sa[15]);
      auto r02 = __builtin_amdgcn_permlane32_swap(a0, a2, false, false);
      auto r13 = __builtin_amdgcn_permlane32_swap(a1, a3, false, false);
      auto r46 = __builtin_amdgcn_permlane32_swap(a4, a6, false, false);
      auto r57 = __builtin_amdgcn_permlane32_swap(a5, a7, false, false);
      u32x4 w0, w1;
      w0[0] = r02[0]; w0[1] = r13[0]; w0[2] = r02[1]; w0[3] = r13[1];
      w1[0] = r46[0]; w1[1] = r57[0]; w1[2] = r46[1]; w1[3] = r57[1];
      const bfrag8 pb0 = __builtin_bit_cast(bfrag8, w0);
      const bfrag8 pb1 = __builtin_bit_cast(bfrag8, w1);
      const unsigned short* vb =
          (const unsigned short*)(arena + 16384 + (size_t)(cur * 2) * 4096);
      bfrag8 vA[2][2];
#pragma unroll
      for (int ks = 0; ks < 2; ++ks)
#pragma unroll
        for (int dh = 0; dh < 2; ++dh)
          vA[ks][dh] = *(const bfrag8*)&vb[(32 * dh + q) * 32 + (((2 * ks + hi) ^ (q & 3)) * 8)];
      __builtin_amdgcn_s_setprio(1);
      o0 = __builtin_amdgcn_mfma_f32_32x32x16_bf16(vA[0][0], pb0, o0, 0, 0, 0);
      o0 = __builtin_amdgcn_mfma_f32_32x32x16_bf16(vA[1][0], pb1, o0, 0, 0, 0);
      o1 = __builtin_amdgcn_mfma_f32_32x32x16_bf16(vA[0][1], pb0, o1, 0, 0, 0);
      o1 = __builtin_amdgcn_mfma_f32_32x32x16_bf16(vA[1][1], pb1, o1, 0, 0, 0);
      __builtin_amdgcn_s_setprio(0);
    }
    if (do1) {
      if (t1 == qt) {
#pragma unroll
        for (int r = 0; r < 16; ++r) {
          const int crow = (r & 3) + 8 * (r >> 2) + 4 * hi;
          if (crow > q) sb[r] = NEG;
        }
      }
#pragma unroll
      for (int r = 0; r < 16; ++r) sb[r] = __builtin_exp2f(sb[r] - FIXM);
      {
        float s8[8];
#pragma unroll
        for (int r = 0; r < 8; ++r) s8[r] = sb[2 * r] + sb[2 * r + 1];
#pragma unroll
        for (int r = 0; r < 4; ++r) s8[r] += s8[r + 4];
        lp += (s8[0] + s8[2]) + (s8[1] + s8[3]);
      }
      const unsigned int a0 = pack2(sb[0],  sb[1]),  a1 = pack2(sb[2],  sb[3]);
      const unsigned int a2 = pack2(sb[4],  sb[5]),  a3 = pack2(sb[6],  sb[7]);
      const unsigned int a4 = pack2(sb[8],  sb[9]),  a5 = pack2(sb[10], sb[11]);
      const unsigned int a6 = pack2(sb[12], sb[13]), a7 = pack2(sb[14], sb[15]);
      auto r02 = __builtin_amdgcn_permlane32_swap(a0, a2, false, false);
      auto r13 = __builtin_amdgcn_permlane32_swap(a1, a3, false, false);
      auto r46 = __builtin_amdgcn_permlane32_swap(a4, a6, false, false);
      auto r57 = __builtin_amdgcn_permlane32_swap(a5, a7, false, false);
      u32x4 w0, w1;
      w0[0] = r02[0]; w0[1] = r13[0]; w0[2] = r02[1]; w0[3] = r13[1];
      w1[0] = r46[0]; w1[1] = r57[0]; w1[2] = r46[1]; w1[3] = r57[1];
      const bfrag8 pb0 = __builtin_bit_cast(bfrag8, w0);
      const bfrag8 pb1 = __builtin_bit_cast(bfrag8, w1);
      const unsigned short* vb =
          (const unsigned short*)(arena + 16384 + (size_t)(cur * 2 + 1) * 4096);
      bfrag8 vA[2][2];
#pragma unroll
      for (int ks = 0; ks < 2; ++ks)
#pragma unroll
        for (int dh = 0; dh < 2; ++dh)
          vA[ks][dh] = *(const bfrag8*)&vb[(32 * dh + q) * 32 + (((2 * ks + hi) ^ (q & 3)) * 8)];
      __builtin_amdgcn_s_setprio(1);
      o0 = __builtin_amdgcn_mfma_f32_32x32x16_bf16(vA[0][0], pb0, o0, 0, 0, 0);
      o0 = __builtin_amdgcn_mfma_f32_32x32x16_bf16(vA[1][0], pb1, o0, 0, 0, 0);
      o1 = __builtin_amdgcn_mfma_f32_32x32x16_bf16(vA[0][1], pb0, o1, 0, 0, 0);
      o1 = __builtin_amdgcn_mfma_f32_32x32x16_bf16(vA[1][1], pb1, o1, 0, 0, 0);
      __builtin_amdgcn_s_setprio(0);
    }

    // 5) one barrier per pair
    __syncthreads();
  }

  // ---- epilogue: combine lane halves, normalize, store own 32 rows ----
  const float lfull = crosshalf_sum(lp);
  const float inv = 1.f / lfull;

  float* orow = Ob + (size_t)(qr0 + q) * ROWSTRIDE;
#pragma unroll
  for (int r2 = 0; r2 < 4; ++r2) {
    f32x4 s0, s1;
#pragma unroll
    for (int j = 0; j < 4; ++j) {
      s0[j] = o0[4 * r2 + j] * inv;
      s1[j] = o1[4 * r2 + j] * inv;
    }
    *(f32x4*)(orow + 8 * r2 + 4 * hi) = s0;
    *(f32x4*)(orow + 32 + 8 * r2 + 4 * hi) = s1;
  }
}

// ---------------------------------------------------------------------------
// Fallback if workspace too small (f32 direct; natural-exp domain)
// ---------------------------------------------------------------------------
__global__ __launch_bounds__(256, 4)
void mha_fwd_f32(const float* __restrict__ Qp, const float* __restrict__ Kp,
                 const float* __restrict__ Vp, float* __restrict__ Op) {
  const int bid = blockIdx.x;
  const int qt = 31 - (bid & 31);
  const int bh = bid >> 5;
  const int h = bh & 15;
  const int b = bh >> 4;
  const int tid = threadIdx.x;
  const int w = tid >> 6;
  const int lane = tid & 63;
  const int g = lane >> 4;
  const int c = lane & 15;

  __shared__ __align__(16) unsigned short Pb[4][16 * 64];
  unsigned short* P = Pb[w];

  const size_t base = (size_t)b * BSTRIDE + (size_t)h * D_;
  const float* Qb = Qp + base;
  const float* Kb = Kp + base;
  const float* Vb = Vp + base;
  float* Ob = Op + base;
  const int qr0 = qt * 64 + w * 16;

  bfrag8 qf[2];
  {
    const float* qp = Qb + (size_t)(qr0 + c) * ROWSTRIDE + g * 8;
#pragma unroll
    for (int s = 0; s < 2; ++s) {
      f32x4 a0 = *(const f32x4*)(qp + 32 * s);
      f32x4 a1 = *(const f32x4*)(qp + 32 * s + 4);
      bfrag8 f;
#pragma unroll
      for (int j = 0; j < 4; ++j) {
        f[j] = (short)f2bf(a0[j] * 0.125f);
        f[j + 4] = (short)f2bf(a1[j] * 0.125f);
      }
      qf[s] = f;
    }
  }
  float m_i[4], l_i[4];
  f32x4 oacc[4];
#pragma unroll
  for (int i = 0; i < 4; ++i) {
    m_i[i] = -INFINITY; l_i[i] = 0.f;
    oacc[i][0] = oacc[i][1] = oacc[i][2] = oacc[i][3] = 0.f;
  }
  for (int t = 0; t <= qt; ++t) {
    const int kv0 = t * 64;
    const bool diag = (t == qt);
    const int kbmax = diag ? w : 3;
    f32x4 sacc[4];
#pragma unroll
    for (int kb = 0; kb < 4; ++kb) {
      if (kb <= kbmax) {
        f32x4 acc; acc[0] = acc[1] = acc[2] = acc[3] = 0.f;
        const float* kp = Kb + (size_t)(kv0 + kb * 16 + c) * ROWSTRIDE + g * 8;
#pragma unroll
        for (int s = 0; s < 2; ++s) {
          f32x4 a0 = *(const f32x4*)(kp + 32 * s);
          f32x4 a1 = *(const f32x4*)(kp + 32 * s + 4);
          bfrag8 kf;
#pragma unroll
          for (int j = 0; j < 4; ++j) {
            kf[j] = (short)f2bf(a0[j]);
            kf[j + 4] = (short)f2bf(a1[j]);
          }
          acc = __builtin_amdgcn_mfma_f32_16x16x32_bf16(qf[s], kf, acc, 0, 0, 0);
        }
        if (diag && kb == w) {
#pragma unroll
          for (int i = 0; i < 4; ++i)
            if (c > 4 * g + i) acc[i] = -INFINITY;
        }
        sacc[kb] = acc;
      } else {
        sacc[kb][0] = sacc[kb][1] = sacc[kb][2] = sacc[kb][3] = -INFINITY;
      }
    }
    float tmax[4];
#pragma unroll
    for (int i = 0; i < 4; ++i)
      tmax[i] = fmaxf(fmaxf(sacc[0][i], sacc[1][i]), fmaxf(sacc[2][i], sacc[3][i]));
#pragma unroll
    for (int mk = 1; mk <= 8; mk <<= 1)
#pragma unroll
      for (int i = 0; i < 4; ++i) tmax[i] = fmaxf(tmax[i], __shfl_xor(tmax[i], mk));
    float rsum[4];
#pragma unroll
    for (int i = 0; i < 4; ++i) {
      const float mnew = fmaxf(m_i[i], tmax[i]);
      const float sc = __expf(m_i[i] - mnew);
      m_i[i] = mnew;
      float rs = 0.f;
#pragma unroll
      for (int kb = 0; kb < 4; ++kb) {
        const float p = __expf(sacc[kb][i] - mnew);
        sacc[kb][i] = p; rs += p;
      }
      rsum[i] = rs; l_i[i] *= sc;
#pragma unroll
      for (int db = 0; db < 4; ++db) oacc[db][i] *= sc;
    }
#pragma unroll
    for (int mk = 1; mk <= 8; mk <<= 1)
#pragma unroll
      for (int i = 0; i < 4; ++i) rsum[i] += __shfl_xor(rsum[i], mk);
#pragma unroll
    for (int i = 0; i < 4; ++i) l_i[i] += rsum[i];
#pragma unroll
    for (int kb = 0; kb < 4; ++kb) {
      const int col = kb * 16 + c;
      const int chunk = col >> 3;
      const int lo = col & 7;
#pragma unroll
      for (int i = 0; i < 4; ++i) {
        const int row = 4 * g + i;
        P[row * 64 + ((chunk ^ (row & 7)) * 8) + lo] = f2bf(sacc[kb][i]);
      }
    }
    asm volatile("s_waitcnt lgkmcnt(0)" ::: "memory");
    bfrag8 pa[2];
#pragma unroll
    for (int ks = 0; ks < 2; ++ks) {
      const int row = c;
      const int chunk = (4 * ks + g) ^ (row & 7);
      pa[ks] = *(const bfrag8*)&P[row * 64 + chunk * 8];
    }
#pragma unroll
    for (int ks = 0; ks < 2; ++ks) {
      const float* vp = Vb + (size_t)(kv0 + ks * 32 + g * 8) * ROWSTRIDE + c;
#pragma unroll
      for (int db = 0; db < 4; ++db) {
        bfrag8 vf;
#pragma unroll
        for (int j = 0; j < 8; ++j)
          vf[j] = (short)f2bf(vp[(size_t)j * ROWSTRIDE + db * 16]);
        oacc[db] = __builtin_amdgcn_mfma_f32_16x16x32_bf16(pa[ks], vf, oacc[db], 0, 0, 0);
      }
    }
  }
#pragma unroll
  for (int i = 0; i < 4; ++i) {
    const float inv = 1.f / l_i[i];
    const int qq = qr0 + 4 * g + i;
    float* op = Ob + (size_t)qq * ROWSTRIDE + c;
#pragma unroll
    for (int db = 0; db < 4; ++db)
      op[db * 16] = oacc[db][i] * inv;
  }
}

extern "C" void kernel_launch(void* const* d_in, const int* in_sizes, int n_in,
                              void* d_out, int out_size, void* d_ws, size_t ws_size,
                              hipStream_t stream) {
  const float* Q = (const float*)d_in[0];
  const float* K = (const float*)d_in[1];
  const float* V = (const float*)d_in[2];
  float* O = (float*)d_out;

  const size_t need = 2 * NTOT * sizeof(unsigned short);
  if (ws_size >= need) {
    unsigned short* Kb = (unsigned short*)d_ws;
    unsigned short* Vt = Kb + NTOT;
    prep_kernel<<<dim3(2048), dim3(256), 0, stream>>>(K, V, Kb, Vt);
    mha_fwd_c64<<<dim3(1024), dim3(256), 0, stream>>>(Q, Kb, Vt, O);
  } else {
    mha_fwd_f32<<<dim3(2048), dim3(256), 0, stream>>>(Q, K, V, O);
  }
}

// Round 25
// 87.747 us; speedup vs baseline: 1.0390x; 1.0390x over previous
//
#include <hip/hip_runtime.h>
#include <hip/hip_bf16.h>

typedef __attribute__((ext_vector_type(8))) short bfrag8;           // 8 bf16
typedef __attribute__((ext_vector_type(8))) unsigned short u16x8;
typedef __attribute__((ext_vector_type(4))) float f32x4;
typedef __attribute__((ext_vector_type(16))) float f32x16;          // 32x32 MFMA C/D
typedef __attribute__((ext_vector_type(4))) unsigned int u32x4;

static constexpr int L_ = 2048;
static constexpr int H_ = 16;
static constexpr int D_ = 64;
static constexpr int ROWSTRIDE = H_ * D_;
static constexpr int BSTRIDE = L_ * H_ * D_;
static constexpr size_t NPH = (size_t)L_ * D_;
static constexpr size_t NTOT = (size_t)4 * H_ * L_ * D_;

// Finite "minus infinity" for masking (exp2(NEG - FIXM) == 0 exactly).
static constexpr float NEG = -1e30f;
// Fixed softmax reference max (exp2 domain); normalizer cancels in O = PV/l.
static constexpr float FIXM = 24.0f;
// (1/sqrt(D)) * log2(e): folded into Q at load time -> scores in exp2 domain.
static constexpr float QS = 0.125f * 1.44269504088896341f;

__device__ __forceinline__ unsigned short f2bf(float f) {
  return __builtin_bit_cast(unsigned short, __float2bfloat16(f));
}
__device__ __forceinline__ unsigned int pack2(float lo, float hi) {
  return (unsigned int)f2bf(lo) | ((unsigned int)f2bf(hi) << 16);
}

// Cross-half (lane i <-> i+32) sum via permlane32_swap builtin (verified r6).
__device__ __forceinline__ float crosshalf_sum(float x) {
  const unsigned xu = __builtin_bit_cast(unsigned int, x);
  auto r = __builtin_amdgcn_permlane32_swap(xu, xu, false, false);
  return __builtin_bit_cast(float, (unsigned int)r[0]) +
         __builtin_bit_cast(float, (unsigned int)r[1]);
}

// ---------------------------------------------------------------------------
// Prep: f32 [B,L,H,D] -> bf16 Kb[B,H,L,D], Vt[B,H,D,L].  (Q not prepped.)
// ---------------------------------------------------------------------------
__global__ __launch_bounds__(256, 4)
void prep_kernel(const float* __restrict__ K, const float* __restrict__ V,
                 unsigned short* __restrict__ Kb, unsigned short* __restrict__ Vt) {
  const int bid = blockIdx.x;
  const int lt = bid & 31;
  const int bh = bid >> 5;
  const int h = bh & 15;
  const int b = bh >> 4;
  const int l0 = lt * 64;
  const int t = threadIdx.x;
  const int lr = t >> 2;
  const int dc = t & 3;

  __shared__ __align__(16) unsigned short vt[64 * 64];

  const size_t src = ((size_t)(b * L_ + l0 + lr) * H_ + h) * D_ + dc * 16;
  const size_t dst = ((size_t)bh * L_ + l0 + lr) * D_ + dc * 16;

  {
    f32x4 a = *(const f32x4*)(K + src),     b4 = *(const f32x4*)(K + src + 4),
          c4 = *(const f32x4*)(K + src + 8), d4 = *(const f32x4*)(K + src + 12);
    u16x8 o0, o1;
#pragma unroll
    for (int j = 0; j < 4; ++j) {
      o0[j] = f2bf(a[j]);  o0[j + 4] = f2bf(b4[j]);
      o1[j] = f2bf(c4[j]); o1[j + 4] = f2bf(d4[j]);
    }
    *(u16x8*)(Kb + dst) = o0;
    *(u16x8*)(Kb + dst + 8) = o1;
  }
  {
    f32x4 a = *(const f32x4*)(V + src),     b4 = *(const f32x4*)(V + src + 4),
          c4 = *(const f32x4*)(V + src + 8), d4 = *(const f32x4*)(V + src + 12);
    u16x8 o0, o1;
#pragma unroll
    for (int j = 0; j < 4; ++j) {
      o0[j] = f2bf(a[j]);  o0[j + 4] = f2bf(b4[j]);
      o1[j] = f2bf(c4[j]); o1[j + 4] = f2bf(d4[j]);
    }
    const int r7 = (lr + (lr >> 3)) & 7;
    *(u16x8*)&vt[lr * 64 + (((dc * 2) ^ r7) * 8)] = o0;
    *(u16x8*)&vt[lr * 64 + (((dc * 2 + 1) ^ r7) * 8)] = o1;
  }
  __syncthreads();
  {
    const int d = t >> 2;
    const int lc = t & 3;
    const int ch = d >> 3, dl = d & 7;
    u16x8 o0, o1;
#pragma unroll
    for (int i = 0; i < 8; ++i) {
      const int r0 = lc * 16 + i;
      const int r1 = lc * 16 + 8 + i;
      o0[i] = vt[r0 * 64 + ((ch ^ ((r0 + (r0 >> 3)) & 7)) * 8) + dl];
      o1[i] = vt[r1 * 64 + ((ch ^ ((r1 + (r1 >> 3)) & 7)) * 8) + dl];
    }
    const size_t vd = ((size_t)bh * D_ + d) * L_ + l0 + lc * 16;
    *(u16x8*)(Vt + vd) = o0;
    *(u16x8*)(Vt + vd + 8) = o1;
  }
}

// ---------------------------------------------------------------------------
// Pair-block staged-LDS flash attention (r23 FINAL: best measured, 87.9us).
// Block = 2 adjacent q-tiles {2p,2p+1}; 4 waves = q-tile x kv-parity (every
// wave computes every iteration). Each iteration stages a PAIR of kv-tiles
// into the alternate 16KB half of a 32KB double buffer: issue-early global->
// regs -> QK MFMA -> RELEASE staged regs (ds_write; die before softmax) ->
// softmax+PV -> ONE barrier. Coalesced Q prologue via LDS (padded rows).
// Grid 2048 (2x residency -> backfill), longest-first, 2-way kv merge = pure
// adds (fixed-max softmax, exp2 domain). All LDS addresses arithmetic.
// launch_bounds(256,4): VGPR 64. Lessons: never tighten the cap (r17);
// no runtime-indexed pointer arrays (r19); release staged regs mid-body
// (r21); coalesce all gathers through LDS (r15/r23).
// ---------------------------------------------------------------------------
__global__ __launch_bounds__(256, 4)
void mha_fwd_db2(const float* __restrict__ Qf,
                 const unsigned short* __restrict__ Kb,
                 const unsigned short* __restrict__ Vt,
                 float* __restrict__ Op) {
  const int bid = blockIdx.x;
  const int plane = bid & 63;               // b*16 + h
  const int p = 31 - (bid >> 6);            // q-tile pair index, longest first
  const int h = plane & 15;
  const int b = plane >> 4;

  const int tid = threadIdx.x;
  const int wv = tid >> 6;
  const int qsel = wv >> 1;                 // 0 -> qt=2p, 1 -> qt=2p+1
  const int pr = wv & 1;                    // kv-tile parity for this wave
  const int lane = tid & 63;
  const int q = lane & 31;
  const int hi = lane >> 5;

  const int qt = 2 * p + qsel;
  const int qr0 = qt * 32;
  const int P = p + 1;                      // iterations (2 kv-tiles each)

  // 32KB double-buffered pair staging; K slab [buf*2+tile]*4096, V at +16384.
  // Prologue transiently overlays arena[0..17408) as f32 qstage[64][68].
  __shared__ __align__(16) unsigned char arena[32768];
  float* mrg = (float*)arena;                          // [2][32][68] f32
  float* lshp = (float*)(arena + 17408);               // [2][32] f32
  float* qstage = (float*)arena;                       // [64][68] f32 (prologue)

  const unsigned short* Kh = Kb + (size_t)plane * NPH;
  const unsigned short* Vh = Vt + (size_t)plane * NPH;
  float* Ob = Op + (size_t)b * BSTRIDE + (size_t)h * D_;

  // staging roles (fixed per thread), XOR-chunk swizzle (write == read)
  const int kr = tid >> 3, kc = tid & 7;    // K: row 0..31, 16B chunk 0..7
  const int vr = tid >> 2, vc = tid & 3;    // V^T: row 0..63, 16B chunk 0..3
  const int kOff = kr * 64 + ((kc ^ (kr & 7)) * 8);   // elements
  const int vOff = vr * 32 + ((vc ^ (vr & 3)) * 8);

  // ---- prologue: kv pair-0 loads issued FIRST (written to LDS later) ----
  u16x8 k0 = *(const u16x8*)(Kh + (size_t)kr * D_ + kc * 8);
  u16x8 v0 = *(const u16x8*)(Vh + (size_t)vr * L_ + vc * 8);
  u16x8 k1 = *(const u16x8*)(Kh + (size_t)(32 + kr) * D_ + kc * 8);
  u16x8 v1 = *(const u16x8*)(Vh + (size_t)vr * L_ + 32 + vc * 8);

  // ---- coalesced Q staging: 64 rows x 256B; 1024 chunks, 4 per thread ----
  {
    const float* qbase = Qf + ((size_t)(b * L_ + 64 * p)) * ROWSTRIDE + h * D_;
#pragma unroll
    for (int i = 0; i < 4; ++i) {
      const int c4 = tid + 256 * i;         // chunk id 0..1023
      const int row = c4 >> 4;              // 0..63
      const int cin = c4 & 15;              // 16B chunk within row
      const f32x4 v = *(const f32x4*)(qbase + (size_t)row * ROWSTRIDE + cin * 4);
      *(f32x4*)&qstage[row * 68 + cin * 4] = v;
    }
  }
  __syncthreads();

  // Q B-frags from LDS (cvt+scale in-reg): lane holds Q[qr0+q][16s+8hi+j]
  bfrag8 qB[4];
#pragma unroll
  for (int s = 0; s < 4; ++s) {
    const float* qrow = &qstage[(qsel * 32 + q) * 68 + 16 * s + 8 * hi];
    const f32x4 lo = *(const f32x4*)qrow;
    const f32x4 hi4 = *(const f32x4*)(qrow + 4);
    bfrag8 f;
#pragma unroll
    for (int j = 0; j < 4; ++j) {
      f[j]     = (short)f2bf(lo[j] * QS);
      f[j + 4] = (short)f2bf(hi4[j] * QS);
    }
    qB[s] = f;
  }
  __syncthreads();                           // qstage dead; arena -> kv slabs

  // write kv pair 0 into buf 0
  {
    *(u16x8*)((unsigned short*)(arena) + kOff) = k0;
    *(u16x8*)((unsigned short*)(arena + 4096) + kOff) = k1;
    *(u16x8*)((unsigned short*)(arena + 16384) + vOff) = v0;
    *(u16x8*)((unsigned short*)(arena + 16384 + 4096) + vOff) = v1;
  }
  __syncthreads();

  float lp = 0.f;
  f32x16 o0 = {};                            // O[q][d = crow + 0..31]
  f32x16 o1 = {};                            // O[q][d = crow + 32..63]

  for (int k = 0; k < P; ++k) {
    const int cur = k & 1;
    const int t = 2 * k + pr;                // my kv-tile this iteration
    const bool more = (k + 1 < P);
    const bool docomp = (t <= qt);

    // 1) issue next pair's global loads
    u16x8 kn0, vn0, kn1, vn1;
    if (more) {
      const int base = (k + 1) * 64;         // rows of tile 2k+2
      kn0 = *(const u16x8*)(Kh + (size_t)(base + kr) * D_ + kc * 8);
      vn0 = *(const u16x8*)(Vh + (size_t)vr * L_ + base + vc * 8);
      kn1 = *(const u16x8*)(Kh + (size_t)(base + 32 + kr) * D_ + kc * 8);
      vn1 = *(const u16x8*)(Vh + (size_t)vr * L_ + base + 32 + vc * 8);
    }

    // 2) QK MFMA (loads land underneath; V-frag reads deferred)
    f32x16 sacc = {};
    if (docomp) {
      const unsigned short* kb =
          (const unsigned short*)(arena + (size_t)(cur * 2 + pr) * 4096);
      bfrag8 kA[4];
#pragma unroll
      for (int s = 0; s < 4; ++s)
        kA[s] = *(const bfrag8*)&kb[q * 64 + (((2 * s + hi) ^ (q & 7)) * 8)];
      __builtin_amdgcn_s_setprio(1);
#pragma unroll
      for (int s = 0; s < 4; ++s)
        sacc = __builtin_amdgcn_mfma_f32_32x32x16_bf16(kA[s], qB[s], sacc, 0, 0, 0);
      __builtin_amdgcn_s_setprio(0);
    }

    // 3) RELEASE staged regs: write into the other buffer NOW (regs die here,
    //    before softmax/PV; target buffer's readers finished last iteration)
    if (more) {
      unsigned char* kslab = arena + (size_t)((cur ^ 1) * 2) * 4096;
      unsigned char* vslab = arena + 16384 + (size_t)((cur ^ 1) * 2) * 4096;
      *(u16x8*)((unsigned short*)kslab + kOff) = kn0;
      *(u16x8*)((unsigned short*)(kslab + 4096) + kOff) = kn1;
      *(u16x8*)((unsigned short*)vslab + vOff) = vn0;
      *(u16x8*)((unsigned short*)(vslab + 4096) + vOff) = vn1;
    }

    // 4) softmax + PV (V-frags read here, after the release)
    if (docomp) {
      if (t == qt) {
#pragma unroll
        for (int r = 0; r < 16; ++r) {
          const int crow = (r & 3) + 8 * (r >> 2) + 4 * hi;
          if (crow > q) sacc[r] = NEG;
        }
      }

#pragma unroll
      for (int r = 0; r < 16; ++r) sacc[r] = __builtin_exp2f(sacc[r] - FIXM);
      {
        float s8[8];
#pragma unroll
        for (int r = 0; r < 8; ++r) s8[r] = sacc[2 * r] + sacc[2 * r + 1];
#pragma unroll
        for (int r = 0; r < 4; ++r) s8[r] += s8[r + 4];
        lp += (s8[0] + s8[2]) + (s8[1] + s8[3]);
      }

      const unsigned int a0 = pack2(sacc[0],  sacc[1]),  a1 = pack2(sacc[2],  sacc[3]);
      const unsigned int a2 = pack2(sacc[4],  sacc[5]),  a3 = pack2(sacc[6],  sacc[7]);
      const unsigned int a4 = pack2(sacc[8],  sacc[9]),  a5 = pack2(sacc[10], sacc[11]);
      const unsigned int a6 = pack2(sacc[12], sacc[13]), a7 = pack2(sacc[14], sacc[15]);
      auto r02 = __builtin_amdgcn_permlane32_swap(a0, a2, false, false);
      auto r13 = __builtin_amdgcn_permlane32_swap(a1, a3, false, false);
      auto r46 = __builtin_amdgcn_permlane32_swap(a4, a6, false, false);
      auto r57 = __builtin_amdgcn_permlane32_swap(a5, a7, false, false);
      u32x4 w0, w1;
      w0[0] = r02[0]; w0[1] = r13[0]; w0[2] = r02[1]; w0[3] = r13[1];
      w1[0] = r46[0]; w1[1] = r57[0]; w1[2] = r46[1]; w1[3] = r57[1];
      const bfrag8 pb0 = __builtin_bit_cast(bfrag8, w0);
      const bfrag8 pb1 = __builtin_bit_cast(bfrag8, w1);

      const unsigned short* vb =
          (const unsigned short*)(arena + 16384 + (size_t)(cur * 2 + pr) * 4096);
      bfrag8 vA[2][2];
#pragma unroll
      for (int ks = 0; ks < 2; ++ks)
#pragma unroll
        for (int dh = 0; dh < 2; ++dh)
          vA[ks][dh] = *(const bfrag8*)&vb[(32 * dh + q) * 32 + (((2 * ks + hi) ^ (q & 3)) * 8)];

      __builtin_amdgcn_s_setprio(1);
      o0 = __builtin_amdgcn_mfma_f32_32x32x16_bf16(vA[0][0], pb0, o0, 0, 0, 0);
      o0 = __builtin_amdgcn_mfma_f32_32x32x16_bf16(vA[1][0], pb1, o0, 0, 0, 0);
      o1 = __builtin_amdgcn_mfma_f32_32x32x16_bf16(vA[0][1], pb0, o1, 0, 0, 0);
      o1 = __builtin_amdgcn_mfma_f32_32x32x16_bf16(vA[1][1], pb1, o1, 0, 0, 0);
      __builtin_amdgcn_s_setprio(0);
    }

    // 5) one barrier per iter: publishes buf[cur^1], fences reads of buf[cur]
    __syncthreads();
  }

  // ---- 2-way kv merge per q-tile (pure adds; arena overlaid) ----
  const float lfull = crosshalf_sum(lp);
  float* mrow = mrg + (qsel * 32 + q) * 68;
  if (pr == 1) {
#pragma unroll
    for (int r2 = 0; r2 < 4; ++r2) {
      f32x4 s0, s1;
#pragma unroll
      for (int j = 0; j < 4; ++j) { s0[j] = o0[4 * r2 + j]; s1[j] = o1[4 * r2 + j]; }
      *(f32x4*)&mrow[8 * r2 + 4 * hi] = s0;
      *(f32x4*)&mrow[32 + 8 * r2 + 4 * hi] = s1;
    }
    if (hi == 0) lshp[qsel * 32 + q] = lfull;
  }
  __syncthreads();
  if (pr == 0) {
    const float inv = 1.f / (lfull + lshp[qsel * 32 + q]);
    float* orow = Ob + (size_t)(qr0 + q) * ROWSTRIDE;
#pragma unroll
    for (int r2 = 0; r2 < 4; ++r2) {
      const f32x4 pB0 = *(const f32x4*)&mrow[8 * r2 + 4 * hi];
      const f32x4 pB1 = *(const f32x4*)&mrow[32 + 8 * r2 + 4 * hi];
      f32x4 s0, s1;
#pragma unroll
      for (int j = 0; j < 4; ++j) {
        s0[j] = (o0[4 * r2 + j] + pB0[j]) * inv;
        s1[j] = (o1[4 * r2 + j] + pB1[j]) * inv;
      }
      *(f32x4*)(orow + 8 * r2 + 4 * hi) = s0;
      *(f32x4*)(orow + 32 + 8 * r2 + 4 * hi) = s1;
    }
  }
}

// ---------------------------------------------------------------------------
// Fallback if workspace too small (f32 direct; natural-exp domain)
// ---------------------------------------------------------------------------
__global__ __launch_bounds__(256, 4)
void mha_fwd_f32(const float* __restrict__ Qp, const float* __restrict__ Kp,
                 const float* __restrict__ Vp, float* __restrict__ Op) {
  const int bid = blockIdx.x;
  const int qt = 31 - (bid & 31);
  const int bh = bid >> 5;
  const int h = bh & 15;
  const int b = bh >> 4;
  const int tid = threadIdx.x;
  const int w = tid >> 6;
  const int lane = tid & 63;
  const int g = lane >> 4;
  const int c = lane & 15;

  __shared__ __align__(16) unsigned short Pb[4][16 * 64];
  unsigned short* P = Pb[w];

  const size_t base = (size_t)b * BSTRIDE + (size_t)h * D_;
  const float* Qb = Qp + base;
  const float* Kb = Kp + base;
  const float* Vb = Vp + base;
  float* Ob = Op + base;
  const int qr0 = qt * 64 + w * 16;

  bfrag8 qf[2];
  {
    const float* qp = Qb + (size_t)(qr0 + c) * ROWSTRIDE + g * 8;
#pragma unroll
    for (int s = 0; s < 2; ++s) {
      f32x4 a0 = *(const f32x4*)(qp + 32 * s);
      f32x4 a1 = *(const f32x4*)(qp + 32 * s + 4);
      bfrag8 f;
#pragma unroll
      for (int j = 0; j < 4; ++j) {
        f[j] = (short)f2bf(a0[j] * 0.125f);
        f[j + 4] = (short)f2bf(a1[j] * 0.125f);
      }
      qf[s] = f;
    }
  }
  float m_i[4], l_i[4];
  f32x4 oacc[4];
#pragma unroll
  for (int i = 0; i < 4; ++i) {
    m_i[i] = -INFINITY; l_i[i] = 0.f;
    oacc[i][0] = oacc[i][1] = oacc[i][2] = oacc[i][3] = 0.f;
  }
  for (int t = 0; t <= qt; ++t) {
    const int kv0 = t * 64;
    const bool diag = (t == qt);
    const int kbmax = diag ? w : 3;
    f32x4 sacc[4];
#pragma unroll
    for (int kb = 0; kb < 4; ++kb) {
      if (kb <= kbmax) {
        f32x4 acc; acc[0] = acc[1] = acc[2] = acc[3] = 0.f;
        const float* kp = Kb + (size_t)(kv0 + kb * 16 + c) * ROWSTRIDE + g * 8;
#pragma unroll
        for (int s = 0; s < 2; ++s) {
          f32x4 a0 = *(const f32x4*)(kp + 32 * s);
          f32x4 a1 = *(const f32x4*)(kp + 32 * s + 4);
          bfrag8 kf;
#pragma unroll
          for (int j = 0; j < 4; ++j) {
            kf[j] = (short)f2bf(a0[j]);
            kf[j + 4] = (short)f2bf(a1[j]);
          }
          acc = __builtin_amdgcn_mfma_f32_16x16x32_bf16(qf[s], kf, acc, 0, 0, 0);
        }
        if (diag && kb == w) {
#pragma unroll
          for (int i = 0; i < 4; ++i)
            if (c > 4 * g + i) acc[i] = -INFINITY;
        }
        sacc[kb] = acc;
      } else {
        sacc[kb][0] = sacc[kb][1] = sacc[kb][2] = sacc[kb][3] = -INFINITY;
      }
    }
    float tmax[4];
#pragma unroll
    for (int i = 0; i < 4; ++i)
      tmax[i] = fmaxf(fmaxf(sacc[0][i], sacc[1][i]), fmaxf(sacc[2][i], sacc[3][i]));
#pragma unroll
    for (int mk = 1; mk <= 8; mk <<= 1)
#pragma unroll
      for (int i = 0; i < 4; ++i) tmax[i] = fmaxf(tmax[i], __shfl_xor(tmax[i], mk));
    float rsum[4];
#pragma unroll
    for (int i = 0; i < 4; ++i) {
      const float mnew = fmaxf(m_i[i], tmax[i]);
      const float sc = __expf(m_i[i] - mnew);
      m_i[i] = mnew;
      float rs = 0.f;
#pragma unroll
      for (int kb = 0; kb < 4; ++kb) {
        const float p = __expf(sacc[kb][i] - mnew);
        sacc[kb][i] = p; rs += p;
      }
      rsum[i] = rs; l_i[i] *= sc;
#pragma unroll
      for (int db = 0; db < 4; ++db) oacc[db][i] *= sc;
    }
#pragma unroll
    for (int mk = 1; mk <= 8; mk <<= 1)
#pragma unroll
      for (int i = 0; i < 4; ++i) rsum[i] += __shfl_xor(rsum[i], mk);
#pragma unroll
    for (int i = 0; i < 4; ++i) l_i[i] += rsum[i];
#pragma unroll
    for (int kb = 0; kb < 4; ++kb) {
      const int col = kb * 16 + c;
      const int chunk = col >> 3;
      const int lo = col & 7;
#pragma unroll
      for (int i = 0; i < 4; ++i) {
        const int row = 4 * g + i;
        P[row * 64 + ((chunk ^ (row & 7)) * 8) + lo] = f2bf(sacc[kb][i]);
      }
    }
    asm volatile("s_waitcnt lgkmcnt(0)" ::: "memory");
    bfrag8 pa[2];
#pragma unroll
    for (int ks = 0; ks < 2; ++ks) {
      const int row = c;
      const int chunk = (4 * ks + g) ^ (row & 7);
      pa[ks] = *(const bfrag8*)&P[row * 64 + chunk * 8];
    }
#pragma unroll
    for (int ks = 0; ks < 2; ++ks) {
      const float* vp = Vb + (size_t)(kv0 + ks * 32 + g * 8) * ROWSTRIDE + c;
#pragma unroll
      for (int db = 0; db < 4; ++db) {
        bfrag8 vf;
#pragma unroll
        for (int j = 0; j < 8; ++j)
          vf[j] = (short)f2bf(vp[(size_t)j * ROWSTRIDE + db * 16]);
        oacc[db] = __builtin_amdgcn_mfma_f32_16x16x32_bf16(pa[ks], vf, oacc[db], 0, 0, 0);
      }
    }
  }
#pragma unroll
  for (int i = 0; i < 4; ++i) {
    const float inv = 1.f / l_i[i];
    const int qq = qr0 + 4 * g + i;
    float* op = Ob + (size_t)qq * ROWSTRIDE + c;
#pragma unroll
    for (int db = 0; db < 4; ++db)
      op[db * 16] = oacc[db][i] * inv;
  }
}

extern "C" void kernel_launch(void* const* d_in, const int* in_sizes, int n_in,
                              void* d_out, int out_size, void* d_ws, size_t ws_size,
                              hipStream_t stream) {
  const float* Q = (const float*)d_in[0];
  const float* K = (const float*)d_in[1];
  const float* V = (const float*)d_in[2];
  float* O = (float*)d_out;

  const size_t need = 2 * NTOT * sizeof(unsigned short);
  if (ws_size >= need) {
    unsigned short* Kb = (unsigned short*)d_ws;
    unsigned short* Vt = Kb + NTOT;
    prep_kernel<<<dim3(2048), dim3(256), 0, stream>>>(K, V, Kb, Vt);
    mha_fwd_db2<<<dim3(2048), dim3(256), 0, stream>>>(Q, Kb, Vt, O);
  } else {
    mha_fwd_f32<<<dim3(2048), dim3(256), 0, stream>>>(Q, K, V, O);
  }
}